// Round 8
// baseline (176.181 us; speedup 1.0000x reference)
//
#include <hip/hip_runtime.h>

#define N_NODES 2000
#define NP      2048    // Sp n-dim padding
#define KB      63      // real k-blocks (k = 2000 padded to 2016 in-block)
#define KB3     66      // padded k-blocks: slabs 63..65 of Sp zero-filled (A=0)
#define BATCH   32
#define DIM     64      // DIM_IN == DIM_OUT
#define EMB     16
#define KI      192     // CHEB_K * DIM_IN
#define WCOLS   12288   // DIM_OUT * KI

typedef __bf16 bf16;
typedef __attribute__((ext_vector_type(8))) __bf16 bf16x8;
typedef __attribute__((ext_vector_type(4))) float  f32x4;

struct alignas(8) bf16x4pk { bf16 v[4]; };

// Packed tile format (4 KB = 256 granules of 16 B) for a 64(row) x 32(k) tile:
//   granule(q, r) = q*64 + r holds elements [row=r][k = q*8 .. q*8+7]

#define Z0   (WCOLS * 32)
#define Z1   (Z0 + N_NODES * 32)
#define Z2   (Z1 + 3 * NP * 32)
// fused-prep grid: [0,2000) softmax rows | [2000,3024) transpose tiles |
// [3024, 3024+2554) prep_small chunks  (Z2/256 == 2554 exactly)
#define PREP_SM_BLK   2554
#define PREP_BLOCKS   (N_NODES + 1024 + PREP_SM_BLK)

// prep_W units: 48 colbases x 25 strips = 1200; packed 2 per 512-thr block
#define PW_BLOCKS 600

// ---------------------------------------------------------------------------
// Kernel A (fused): softmax -> Sp packed | x transpose-pack | wpT2/embp/zero
// (R4-proven form, 256 threads.)
// ---------------------------------------------------------------------------
__global__ __launch_bounds__(256) void prep_fused(
    const float* __restrict__ nv1, const float* __restrict__ nv2,
    bf16* __restrict__ Sp,
    const float* __restrict__ X, bf16* __restrict__ Xtp, bf16* __restrict__ Xbf,
    const float* __restrict__ wp, const float* __restrict__ emb,
    bf16* __restrict__ wpT2, bf16* __restrict__ embp, bf16* __restrict__ Sp63)
{
    const int bid = blockIdx.x;
    const int tid = threadIdx.x;

    if (bid < N_NODES) {
        // ----- softmax(relu(nv1@nv2)) row -> packed Sp tiles -----
        const int row = bid;
        const int j0  = tid * 8;
        __shared__ float sa[EMB];
        __shared__ float wred[4];
        __shared__ float bcast;
        if (tid < EMB) sa[tid] = nv1[row * EMB + tid];
        __syncthreads();

        const bool active = (tid < 250);
        float v[8] = {0,0,0,0,0,0,0,0};
        if (active) {
#pragma unroll
            for (int d = 0; d < EMB; ++d) {
                const float sd = sa[d];
                const float4 q0 = *(const float4*)&nv2[d * N_NODES + j0];
                const float4 q1 = *(const float4*)&nv2[d * N_NODES + j0 + 4];
                v[0] += sd * q0.x; v[1] += sd * q0.y; v[2] += sd * q0.z; v[3] += sd * q0.w;
                v[4] += sd * q1.x; v[5] += sd * q1.y; v[6] += sd * q1.z; v[7] += sd * q1.w;
            }
        }
        float lmax = 0.0f;
#pragma unroll
        for (int jj = 0; jj < 8; ++jj) { v[jj] = fmaxf(v[jj], 0.0f); lmax = fmaxf(lmax, v[jj]); }
#pragma unroll
        for (int off = 32; off > 0; off >>= 1)
            lmax = fmaxf(lmax, __shfl_down(lmax, off, 64));
        if ((tid & 63) == 0) wred[tid >> 6] = lmax;
        __syncthreads();
        if (tid == 0) bcast = fmaxf(fmaxf(wred[0], wred[1]), fmaxf(wred[2], wred[3]));
        __syncthreads();
        const float rmax = bcast;

        float lsum = 0.0f;
        if (active) {
#pragma unroll
            for (int jj = 0; jj < 8; ++jj) { v[jj] = __expf(v[jj] - rmax); lsum += v[jj]; }
        }
#pragma unroll
        for (int off = 32; off > 0; off >>= 1)
            lsum += __shfl_down(lsum, off, 64);
        if ((tid & 63) == 0) wred[tid >> 6] = lsum;
        __syncthreads();
        if (tid == 0) bcast = wred[0] + wred[1] + wred[2] + wred[3];
        __syncthreads();
        const float inv = 1.0f / bcast;

        if (tid < 252) {   // threads 250,251 write the k 2000..2015 zero pad
            bf16x8 pk;
#pragma unroll
            for (int jj = 0; jj < 8; ++jj)
                pk[jj] = (bf16)(active ? v[jj] * inv : 0.0f);
            const int kb = j0 >> 5, q = (j0 >> 3) & 3;
            const int nt = row >> 6, r = row & 63;
            *(bf16x8*)&Sp[((size_t)(kb * 32 + nt) * 256 + q * 64 + r) * 8] = pk;
        }
    } else if (bid < N_NODES + 1024) {
        // ----- x [b][m][c] fp32 -> xTp packed + xbf row-major bf16 -----
        const int t  = bid - N_NODES;
        const int b  = t >> 5;
        const int m0 = (t & 31) * 64;
        __shared__ bf16 T[64][72];
#pragma unroll
        for (int i = 0; i < 4; ++i) {
            int idx = i * 256 + tid;
            int r  = idx >> 4;
            int c4 = (idx & 15) * 4;
            int m  = m0 + r;
            float4 v = make_float4(0.f, 0.f, 0.f, 0.f);
            if (m < N_NODES)
                v = *(const float4*)&X[((size_t)b * N_NODES + m) * DIM + c4];
            bf16x4pk pk;
            pk.v[0] = (bf16)v.x; pk.v[1] = (bf16)v.y;
            pk.v[2] = (bf16)v.z; pk.v[3] = (bf16)v.w;
            if (m < N_NODES)
                *(bf16x4pk*)&Xbf[((size_t)b * N_NODES + m) * DIM + c4] = pk;
            T[c4 + 0][r] = pk.v[0];
            T[c4 + 1][r] = pk.v[1];
            T[c4 + 2][r] = pk.v[2];
            T[c4 + 3][r] = pk.v[3];
        }
        __syncthreads();
#pragma unroll
        for (int i = 0; i < 2; ++i) {
            int idx = i * 256 + tid;
            int c   = idx >> 3;
            int mch = idx & 7;
            int kb  = (m0 >> 5) + (mch >> 2);
            if (kb < KB) {
                int q = mch & 3;
                bf16x8 vv = *(const bf16x8*)&T[c][mch * 8];
                *(bf16x8*)&Xtp[((size_t)(b * KB3 + kb) * 256 + q * 64 + c) * 8] = vv;
            }
        }
    } else {
        // ----- wpT2 / embp pack + zero-fill Sp slabs 63..65 -----
        int idx = (bid - N_NODES - 1024) * 256 + tid;
        if (idx < Z0) {
            int col = idx >> 5, d = idx & 31;
            int o  = col / KI;
            int kk = col - o * KI;
            int cheb = kk >> 6, i = kk & 63;
            float v = (d < EMB) ? wp[(((d * 3 + cheb) * 64 + i) * 64) + o] : 0.0f;
            wpT2[idx] = (bf16)v;
        } else if (idx < Z1) {
            int j = idx - Z0;
            int n = j >> 5, d = j & 31;
            float v = (d < EMB) ? emb[n * EMB + d] : 0.0f;
            embp[j] = (bf16)v;
        } else if (idx < Z2) {
            Sp63[idx - Z1] = (bf16)0.0f;
        }
    }
}

// ---------------------------------------------------------------------------
// Kernel 3 (MERGED): spmm k-split 8-wave (2x occupancy) + prep_W colocated.
// R2..R7 survey: 2-buf drain / ring-3 / ring-4 counted-vmcnt / reg-direct all
// land 43-51 us at 8 spmm waves/CU, MfmaUtil ~15% — the invariant across all
// was OCCUPANCY. R8: 512-thread blocks; waves 0-3 compute the 128x64 tile
// over k-blocks 0..32, waves 4-7 over 33..65 (reg-direct, no k-loop
// barriers); one __syncthreads; upper waves dump acc to LDS (lane-contiguous
// per reg-index -> conflict-free); lower waves add + proven epilogue.
// 16 spmm waves/CU at UNCHANGED total traffic.
// ---------------------------------------------------------------------------
__global__ __launch_bounds__(512, 4) void spmm_ks(
    const bf16* __restrict__ Ap, const bf16* __restrict__ Btp,
    bf16* __restrict__ Ybf, bf16* __restrict__ Ytp,
    const bf16* __restrict__ embp, const bf16* __restrict__ wpT2,
    bf16* __restrict__ W, int write_ytp)
{
    __shared__ __align__(16) char smem[32768];   // spmm: f32 reduce; PW: 2x Cs
    const int bid  = blockIdx.x;
    const int tid  = threadIdx.x;
    const int lane = tid & 63;
    const int l15  = lane & 15, quad = (lane >> 4) & 3;

    if (bid < 512) {
        // ================= spmm role (k-split reg-direct) =================
        const int wave = tid >> 6;           // 0..7
        const int kh   = wave >> 2;          // k-half
        const int w4   = wave & 3;           // tile-role within half

        const int kx = bid & 7, j = bid >> 3;   // kx = XCD (dispatch round-robin)
        const int ntB = (j & 7) + 8 * (kx & 1);
        const int b   = ((j >> 3) << 2) + (kx >> 1);
        const int n0  = ntB * 128;

        // A: wave-private 64-row tile nt = ntB*2 + (w4>>1);
        //    granule = quad*64 + (w4&1)*32 + t*16 + l15   (t = 0,1)
        const bf16* aptr = Ap + ((size_t)(ntB * 2 + (w4 >> 1)) * 256
                                 + quad * 64 + (w4 & 1) * 32 + l15) * 8
                              + (size_t)(kh * 33) * 65536;
        // B: granule = quad*64 + t*16 + l15 (t = 0..3)
        const bf16* bptr = Btp + ((size_t)(b * KB3) * 256
                                  + quad * 64 + l15) * 8
                               + (size_t)(kh * 33) * 2048;

        f32x4 acc[2][4] = {};

        bf16x8 A0, A1, B0, B1, B2, B3;
        A0 = *(const bf16x8*)(aptr);
        A1 = *(const bf16x8*)(aptr + 128);
        B0 = *(const bf16x8*)(bptr);
        B1 = *(const bf16x8*)(bptr + 128);
        B2 = *(const bf16x8*)(bptr + 256);
        B3 = *(const bf16x8*)(bptr + 384);
#pragma unroll 2
        for (int s = 0; s < 33; ++s) {
            bf16x8 nA0, nA1, nB0, nB1, nB2, nB3;
            if (s + 1 < 33) {
                const bf16* pa = aptr + (size_t)(s + 1) * 65536;
                const bf16* pb = bptr + (size_t)(s + 1) * 2048;
                nA0 = *(const bf16x8*)(pa);
                nA1 = *(const bf16x8*)(pa + 128);
                nB0 = *(const bf16x8*)(pb);
                nB1 = *(const bf16x8*)(pb + 128);
                nB2 = *(const bf16x8*)(pb + 256);
                nB3 = *(const bf16x8*)(pb + 384);
            }
            acc[0][0] = __builtin_amdgcn_mfma_f32_16x16x32_bf16(A0, B0, acc[0][0], 0, 0, 0);
            acc[0][1] = __builtin_amdgcn_mfma_f32_16x16x32_bf16(A0, B1, acc[0][1], 0, 0, 0);
            acc[0][2] = __builtin_amdgcn_mfma_f32_16x16x32_bf16(A0, B2, acc[0][2], 0, 0, 0);
            acc[0][3] = __builtin_amdgcn_mfma_f32_16x16x32_bf16(A0, B3, acc[0][3], 0, 0, 0);
            acc[1][0] = __builtin_amdgcn_mfma_f32_16x16x32_bf16(A1, B0, acc[1][0], 0, 0, 0);
            acc[1][1] = __builtin_amdgcn_mfma_f32_16x16x32_bf16(A1, B1, acc[1][1], 0, 0, 0);
            acc[1][2] = __builtin_amdgcn_mfma_f32_16x16x32_bf16(A1, B2, acc[1][2], 0, 0, 0);
            acc[1][3] = __builtin_amdgcn_mfma_f32_16x16x32_bf16(A1, B3, acc[1][3], 0, 0, 0);
            A0 = nA0; A1 = nA1;
            B0 = nB0; B1 = nB1; B2 = nB2; B3 = nB3;
        }

        // ---- cross-half reduce: upper waves stash, lower waves add ----
        float* red = (float*)smem;           // [32 reg-idx][256 = w4*64+lane]
        if (kh == 1) {
#pragma unroll
            for (int rt = 0; rt < 2; ++rt)
#pragma unroll
                for (int ct = 0; ct < 4; ++ct)
#pragma unroll
                    for (int r = 0; r < 4; ++r)
                        red[((rt * 4 + ct) * 4 + r) * 256 + w4 * 64 + lane]
                            = acc[rt][ct][r];
        }
        __syncthreads();
        if (kh == 0) {
#pragma unroll
            for (int rt = 0; rt < 2; ++rt)
#pragma unroll
                for (int ct = 0; ct < 4; ++ct)
#pragma unroll
                    for (int r = 0; r < 4; ++r)
                        acc[rt][ct][r] +=
                            red[((rt * 4 + ct) * 4 + r) * 256 + w4 * 64 + lane];

            // Epilogue. C/D layout: col = lane&15, row = quad*4 + reg
#pragma unroll
            for (int rt = 0; rt < 2; ++rt) {
                const int nbase = n0 + (w4 >> 1) * 64 + (w4 & 1) * 32
                                  + rt * 16 + quad * 4;
#pragma unroll
                for (int ct = 0; ct < 4; ++ct) {
                    const int c = ct * 16 + l15;
#pragma unroll
                    for (int r = 0; r < 4; ++r) {
                        int n = nbase + r;
                        if (n < N_NODES)
                            Ybf[((size_t)b * N_NODES + n) * DIM + c] = (bf16)acc[rt][ct][r];
                    }
                    if (write_ytp && nbase + 4 <= N_NODES) {
                        const int kb2 = nbase >> 5;
                        const int kq  = (nbase & 31) >> 3;
                        const int j4  = nbase & 7;       // 0 or 4
                        bf16x4pk pk;
                        pk.v[0] = (bf16)acc[rt][ct][0];
                        pk.v[1] = (bf16)acc[rt][ct][1];
                        pk.v[2] = (bf16)acc[rt][ct][2];
                        pk.v[3] = (bf16)acc[rt][ct][3];
                        *(bf16x4pk*)&Ytp[((size_t)(b * KB3 + kb2) * 256 + kq * 64 + c) * 8 + j4] = pk;
                    }
                }
            }
        }
    } else {
        // ============ prep_W role: two independent 256-thr units ============
        // W[n][col] = sum_d embp[n][d] * wpT2[col][d]  (bf16 out)
        // half h = tid>>8 runs unit (pid*2 + h); barrier counts identical
        // across halves (10 each) -> block-wide __syncthreads is safe.
        bf16 (*Cs)[16][264] = (bf16(*)[16][264])smem;   // 2 x 8.4 KB

        const int half = tid >> 8;
        const int t2   = tid & 255;
        const int w2   = t2 >> 6;            // 0..3 within half

        const int unit    = (bid - 512) * 2 + half;
        const int colbase = (unit % 48) * 256;
        const int ng0     = (unit / 48) * 5;

        bf16x8 bfr[4];
#pragma unroll
        for (int ct = 0; ct < 4; ++ct) {
            const int col = colbase + w2 * 64 + ct * 16 + l15;
            bfr[ct] = *(const bf16x8*)&wpT2[(size_t)col * 32 + quad * 8];
        }
        bf16x8 afs[5];
#pragma unroll
        for (int g = 0; g < 5; ++g)
            afs[g] = *(const bf16x8*)&embp[(size_t)((ng0 + g) * 16 + l15) * 32 + quad * 8];
        const f32x4 zero = {};

#pragma unroll
        for (int g = 0; g < 5; ++g) {
            const int n0 = (ng0 + g) * 16;
#pragma unroll
            for (int ct = 0; ct < 4; ++ct) {
                f32x4 acc = __builtin_amdgcn_mfma_f32_16x16x32_bf16(afs[g], bfr[ct], zero, 0, 0, 0);
#pragma unroll
                for (int r = 0; r < 4; ++r)
                    Cs[half][quad * 4 + r][w2 * 64 + ct * 16 + l15] = (bf16)acc[r];
            }
            __syncthreads();
            {
                const int row = t2 >> 4;
                const int c16 = (t2 & 15) * 16;
                bf16x8 v0 = *(const bf16x8*)&Cs[half][row][c16];
                bf16x8 v1 = *(const bf16x8*)&Cs[half][row][c16 + 8];
                bf16* dst = &W[(size_t)(n0 + row) * WCOLS + colbase + c16];
                *(bf16x8*)dst       = v0;
                *(bf16x8*)(dst + 8) = v1;
            }
            __syncthreads();   // Cs fully consumed before next group's MFMA
        }
    }
}

// ---------------------------------------------------------------------------
// Kernel 5: per-node combine (bf16 inputs) — proven baseline form.
// ---------------------------------------------------------------------------
__global__ __launch_bounds__(256) void combine_node(
    const bf16* __restrict__ xbf, const bf16* __restrict__ y1bf,
    const bf16* __restrict__ y2bf, const float* __restrict__ emb,
    const float* __restrict__ bp, const bf16* __restrict__ W,
    float* __restrict__ out)
{
    const int n   = blockIdx.x;
    const int tid = threadIdx.x;
    const int lane = tid & 63, wave = tid >> 6;
    const int l15 = lane & 15, quad = lane >> 4;

    __shared__ bf16 As[BATCH][200];
    __shared__ bf16 Ws[DIM][200];
    __shared__ float bias_s[DIM];
    __shared__ float emb_s[EMB];

    if (tid < EMB) emb_s[tid] = emb[n * EMB + tid];

    {
        const int b  = tid >> 3;
        const int c8 = (tid & 7) * 8;
        const size_t base = ((size_t)b * N_NODES + n) * DIM + c8;
        bf16x8 vx = *(const bf16x8*)&xbf [base];
        bf16x8 v1 = *(const bf16x8*)&y1bf[base];
        bf16x8 v2 = *(const bf16x8*)&y2bf[base];
        bf16x8 p2;
#pragma unroll
        for (int e = 0; e < 8; ++e)
            p2[e] = (bf16)(2.0f * (float)v2[e] - (float)vx[e]);
        *(bf16x8*)&As[b][c8]       = vx;
        *(bf16x8*)&As[b][64 + c8]  = v1;
        *(bf16x8*)&As[b][128 + c8] = p2;
    }
    {
        const bf16* Wn = W + (size_t)n * WCOLS;
#pragma unroll
        for (int jj = 0; jj < 6; ++jj) {
            int chunk = jj * 256 + tid;
            int o  = chunk / 24;
            int kc = chunk - o * 24;
            bf16x8 v = *(const bf16x8*)&Wn[(size_t)chunk * 8];
            *(bf16x8*)&Ws[o][kc * 8] = v;
        }
    }
    __syncthreads();

    if (tid < DIM) {
        float s = 0.0f;
#pragma unroll
        for (int d = 0; d < EMB; ++d) s += emb_s[d] * bp[d * DIM + tid];
        bias_s[tid] = s;
    }

    bf16x8 af[2][6];
#pragma unroll
    for (int mt = 0; mt < 2; ++mt)
#pragma unroll
        for (int ks = 0; ks < 6; ++ks)
            af[mt][ks] = *(const bf16x8*)&As[mt * 16 + l15][ks * 32 + quad * 8];

    f32x4 acc[2] = {};
#pragma unroll
    for (int ks = 0; ks < 6; ++ks) {
        bf16x8 bfr = *(const bf16x8*)&Ws[wave * 16 + l15][ks * 32 + quad * 8];
        acc[0] = __builtin_amdgcn_mfma_f32_16x16x32_bf16(af[0][ks], bfr, acc[0], 0, 0, 0);
        acc[1] = __builtin_amdgcn_mfma_f32_16x16x32_bf16(af[1][ks], bfr, acc[1], 0, 0, 0);
    }
    __syncthreads();

    const int o = wave * 16 + l15;
    const float bv = bias_s[o];
#pragma unroll
    for (int mt = 0; mt < 2; ++mt)
#pragma unroll
        for (int r = 0; r < 4; ++r) {
            int b = mt * 16 + quad * 4 + r;
            out[((size_t)b * N_NODES + n) * DIM + o] = acc[mt][r] + bv;
        }
}

// ---------------------------------------------------------------------------
extern "C" void kernel_launch(void* const* d_in, const int* in_sizes, int n_in,
                              void* d_out, int out_size, void* d_ws, size_t ws_size,
                              hipStream_t stream) {
    const float* x   = (const float*)d_in[0];  // [32,2000,64]
    const float* emb = (const float*)d_in[1];  // [2000,16]
    const float* nv1 = (const float*)d_in[2];  // [2000,16]
    const float* nv2 = (const float*)d_in[3];  // [16,2000]
    const float* wp  = (const float*)d_in[4];  // [16,3,64,64]
    const float* bp  = (const float*)d_in[5];  // [16,64]
    float* out = (float*)d_out;                // [32,2000,64]

    char* w = (char*)d_ws;
    bf16* Sp   = (bf16*)w;  w += (size_t)KB3 * NP * 32 * 2;           //  8.65 MB
    bf16* xTp  = (bf16*)w;  w += (size_t)BATCH * KB3 * DIM * 32 * 2;  //  8.65 MB
    bf16* y1Tp = (bf16*)w;  w += (size_t)BATCH * KB3 * DIM * 32 * 2;  //  8.65 MB
    bf16* xbf  = (bf16*)w;  w += (size_t)BATCH * N_NODES * DIM * 2;   //  8.19 MB
    bf16* y1bf = (bf16*)w;  w += (size_t)BATCH * N_NODES * DIM * 2;   //  8.19 MB
    bf16* y2bf = (bf16*)w;  w += (size_t)BATCH * N_NODES * DIM * 2;   //  8.19 MB
    bf16* wpT2 = (bf16*)w;  w += (size_t)WCOLS * 32 * 2;              //  0.79 MB
    bf16* embp = (bf16*)w;  w += (size_t)N_NODES * 32 * 2;            //  0.13 MB
    bf16* W    = (bf16*)w;                                            // 49.15 MB

    prep_fused<<<PREP_BLOCKS, 256, 0, stream>>>(
        nv1, nv2, Sp, x, xTp, xbf, wp, emb, wpT2, embp,
        Sp + (size_t)63 * NP * 32);
    // spmm1 + prep_W colocated: 512 spmm blocks + 600 dual-unit prep_W blocks
    spmm_ks<<<512 + PW_BLOCKS, 512, 0, stream>>>(Sp, xTp, y1bf, y1Tp, embp, wpT2, W, 1);
    spmm_ks<<<512, 512, 0, stream>>>(Sp, y1Tp, y2bf, y1Tp, embp, wpT2, W, 0);
    combine_node<<<N_NODES, 256, 0, stream>>>(xbf, y1bf, y2bf, emb, bp, W, out);
}

// Round 9
// 173.635 us; speedup vs baseline: 1.0147x; 1.0147x over previous
//
#include <hip/hip_runtime.h>

#define N_NODES 2000
#define NP      2048    // Sp n-dim padding
#define KB      63      // real k-blocks (k = 2000 padded to 2016 in-block)
#define KB3     66      // padded k-blocks: slabs 63..65 of Sp zero-filled (A=0)
#define BATCH   32
#define DIM     64      // DIM_IN == DIM_OUT
#define EMB     16
#define KI      192     // CHEB_K * DIM_IN
#define WCOLS   12288   // DIM_OUT * KI

typedef __bf16 bf16;
typedef __attribute__((ext_vector_type(8))) __bf16 bf16x8;
typedef __attribute__((ext_vector_type(4))) float  f32x4;

struct alignas(8) bf16x4pk { bf16 v[4]; };

// Async global->LDS DMA, 16 B per lane (lane-contiguous within each wave).
__device__ __forceinline__ void gl_lds16(const bf16* g, bf16* l) {
    __builtin_amdgcn_global_load_lds(
        (__attribute__((address_space(1))) void*)(g),
        (__attribute__((address_space(3))) void*)(l), 16, 0, 0);
}

// Packed tile format (4 KB = 256 granules of 16 B) for a 64(row) x 32(k) tile:
//   granule(q, r) = q*64 + r holds elements [row=r][k = q*8 .. q*8+7]
// Fragment read hits 16 consecutive granules per quad-phase -> conflict-free
// ds_read_b128.

#define Z0   (WCOLS * 32)
#define Z1   (Z0 + N_NODES * 32)
#define Z2   (Z1 + 3 * NP * 32)
// fused-prep grid: [0,500) softmax 4-row blocks | [500,1524) transpose tiles |
// [1524, 1524+2554) prep_small chunks  (Z2/256 == 2554 exactly)
#define SM_BLOCKS     500
#define PREP_SM_BLK   2554
#define PREP_BLOCKS   (SM_BLOCKS + 1024 + PREP_SM_BLK)

// prep_W coarse blocks: 48 colbases x 25 strips (5 n-groups each) = 1200
#define PW_BLOCKS 1200

// ---------------------------------------------------------------------------
// Kernel A (fused): softmax -> Sp packed | x transpose-pack | wpT2/embp/zero
// R9: softmax phase rewritten as 500 blocks x 4 rows, ONE WAVE PER ROW.
//  - reductions are pure __shfl_xor butterflies: zero barriers, zero LDS
//  - nv1 loads are wave-uniform -> scalar loads
//  - the block's 4 waves jointly fill every Sp 64-B line (rows 4R..4R+3):
//    previously those 4 rows came from 4 DIFFERENT blocks on different XCDs
//    -> cross-XCD partial-line dirty slivers -> partial-sector writebacks.
// ---------------------------------------------------------------------------
__global__ __launch_bounds__(256) void prep_fused(
    const float* __restrict__ nv1, const float* __restrict__ nv2,
    bf16* __restrict__ Sp,
    const float* __restrict__ X, bf16* __restrict__ Xtp, bf16* __restrict__ Xbf,
    const float* __restrict__ wp, const float* __restrict__ emb,
    bf16* __restrict__ wpT2, bf16* __restrict__ embp, bf16* __restrict__ Sp63)
{
    const int bid = blockIdx.x;
    const int tid = threadIdx.x;

    if (bid < SM_BLOCKS) {
        // ----- softmax(relu(nv1@nv2)) 4 rows/block, wave-local -----
        const int row = bid * 4 + (tid >> 6);   // wave = row
        const int l   = tid & 63;
        const int nt  = row >> 6, r = row & 63;
        const bool real3 = (l < 58);            // chunk 3: j >= 2000 for l >= 58

        float v[4][8] = {};
#pragma unroll
        for (int d = 0; d < EMB; ++d) {
            const float sd = nv1[row * EMB + d];   // wave-uniform -> s_load
#pragma unroll
            for (int c = 0; c < 4; ++c) {
                if (c == 3 && !real3) continue;    // avoid OOB nv2 reads
                const int j = c * 512 + l * 8;
                const float4 q0 = *(const float4*)&nv2[d * N_NODES + j];
                const float4 q1 = *(const float4*)&nv2[d * N_NODES + j + 4];
                v[c][0] += sd * q0.x; v[c][1] += sd * q0.y;
                v[c][2] += sd * q0.z; v[c][3] += sd * q0.w;
                v[c][4] += sd * q1.x; v[c][5] += sd * q1.y;
                v[c][6] += sd * q1.z; v[c][7] += sd * q1.w;
            }
        }
        // relu + wave max (masked lanes hold 0, matching old 0.0 baseline)
        float lmax = 0.0f;
#pragma unroll
        for (int c = 0; c < 4; ++c)
#pragma unroll
            for (int jj = 0; jj < 8; ++jj) {
                v[c][jj] = fmaxf(v[c][jj], 0.0f);
                lmax = fmaxf(lmax, v[c][jj]);
            }
#pragma unroll
        for (int off = 32; off > 0; off >>= 1)
            lmax = fmaxf(lmax, __shfl_xor(lmax, off, 64));
        const float rmax = lmax;

        float lsum = 0.0f;
#pragma unroll
        for (int c = 0; c < 4; ++c) {
            if (c == 3 && !real3) continue;        // keep masked v == 0
#pragma unroll
            for (int jj = 0; jj < 8; ++jj) {
                v[c][jj] = __expf(v[c][jj] - rmax);
                lsum += v[c][jj];
            }
        }
#pragma unroll
        for (int off = 32; off > 0; off >>= 1)
            lsum += __shfl_xor(lsum, off, 64);
        const float inv = 1.0f / lsum;

        // write: chunks 0-2 all lanes; chunk 3 lanes l<60 (l=58,59 write the
        // k 2000..2015 zero pad: v==0 there). Same domain as old tid<252.
#pragma unroll
        for (int c = 0; c < 4; ++c) {
            if (c == 3 && l >= 60) continue;
            const int j  = c * 512 + l * 8;
            const int kb = j >> 5, q = (j >> 3) & 3;
            bf16x8 pk;
#pragma unroll
            for (int jj = 0; jj < 8; ++jj)
                pk[jj] = (bf16)(v[c][jj] * inv);
            *(bf16x8*)&Sp[((size_t)(kb * 32 + nt) * 256 + q * 64 + r) * 8] = pk;
        }
    } else if (bid < SM_BLOCKS + 1024) {
        // ----- x [b][m][c] fp32 -> xTp packed + xbf row-major bf16 -----
        const int t  = bid - SM_BLOCKS;
        const int b  = t >> 5;
        const int m0 = (t & 31) * 64;
        __shared__ bf16 T[64][72];
#pragma unroll
        for (int i = 0; i < 4; ++i) {
            int idx = i * 256 + tid;
            int r  = idx >> 4;
            int c4 = (idx & 15) * 4;
            int m  = m0 + r;
            float4 v = make_float4(0.f, 0.f, 0.f, 0.f);
            if (m < N_NODES)
                v = *(const float4*)&X[((size_t)b * N_NODES + m) * DIM + c4];
            bf16x4pk pk;
            pk.v[0] = (bf16)v.x; pk.v[1] = (bf16)v.y;
            pk.v[2] = (bf16)v.z; pk.v[3] = (bf16)v.w;
            if (m < N_NODES)
                *(bf16x4pk*)&Xbf[((size_t)b * N_NODES + m) * DIM + c4] = pk;
            T[c4 + 0][r] = pk.v[0];
            T[c4 + 1][r] = pk.v[1];
            T[c4 + 2][r] = pk.v[2];
            T[c4 + 3][r] = pk.v[3];
        }
        __syncthreads();
#pragma unroll
        for (int i = 0; i < 2; ++i) {
            int idx = i * 256 + tid;
            int c   = idx >> 3;
            int mch = idx & 7;
            int kb  = (m0 >> 5) + (mch >> 2);
            if (kb < KB) {
                int q = mch & 3;
                bf16x8 vv = *(const bf16x8*)&T[c][mch * 8];
                *(bf16x8*)&Xtp[((size_t)(b * KB3 + kb) * 256 + q * 64 + c) * 8] = vv;
            }
        }
    } else {
        // ----- wpT2 / embp pack + zero-fill Sp slabs 63..65 -----
        int idx = (bid - SM_BLOCKS - 1024) * 256 + tid;
        if (idx < Z0) {
            int col = idx >> 5, d = idx & 31;
            int o  = col / KI;
            int kk = col - o * KI;
            int cheb = kk >> 6, i = kk & 63;
            float v = (d < EMB) ? wp[(((d * 3 + cheb) * 64 + i) * 64) + o] : 0.0f;
            wpT2[idx] = (bf16)v;
        } else if (idx < Z1) {
            int j = idx - Z0;
            int n = j >> 5, d = j & 31;
            float v = (d < EMB) ? emb[n * EMB + d] : 0.0f;
            embp[j] = (bf16)v;
        } else if (idx < Z2) {
            Sp63[idx - Z1] = (bf16)0.0f;
        }
    }
}

// ---------------------------------------------------------------------------
// Kernel 3a (MERGED): spmm1 (2-kb stages, 48 KB LDS, 3 blocks/CU) + prep_W.
// R4-proven form (46.4 us; at the documented ~320-360 TF plateau for this
// GEMM size/structure class — R5-R8 showed pipelining/occupancy don't move it).
// ---------------------------------------------------------------------------
__global__ __launch_bounds__(256, 3) void spmm1_plus(
    const bf16* __restrict__ Ap, const bf16* __restrict__ Btp,
    bf16* __restrict__ Ybf, bf16* __restrict__ Ytp,
    const bf16* __restrict__ embp, const bf16* __restrict__ wpT2,
    bf16* __restrict__ W)
{
    __shared__ __align__(16) char smem[49152];   // 48 KB: union of both roles
    const int bid  = blockIdx.x;
    const int tid  = threadIdx.x;
    const int lane = tid & 63, wave = tid >> 6;
    const int l15  = lane & 15, quad = lane >> 4;

    if (bid < 512) {
        // ================= spmm role =================
        bf16* As = (bf16*)smem;             // [2][2*4096]  (2 x 16 KB)
        bf16* Bs = (bf16*)(smem + 32768);   // [2][2*2048]  (2 x  8 KB)

        const int kx = bid & 7, j = bid >> 3;   // kx = XCD (dispatch round-robin)
        const int ntB = (j & 7) + 8 * (kx & 1);
        const int b   = ((j >> 3) << 2) + (kx >> 1);
        const int n0  = ntB * 128;

        const bf16* aslab = Ap  + (size_t)(ntB * 2) * 2048 + tid * 8;  // + kb*65536
        const bf16* bslab = Btp + (size_t)(b * KB3) * 2048 + tid * 8;  // + kb*2048

#define DMA_STAGE2(buf, kb0_) {                                          \
        _Pragma("unroll")                                                \
        for (int jj = 0; jj < 2; ++jj) {                                 \
            const bf16* pa = aslab + (size_t)(kb0_ + jj) * (32 * 2048);  \
            const bf16* pb = bslab + (size_t)(kb0_ + jj) * 2048;         \
            gl_lds16(pa,        &As[(buf) * 8192 + jj * 4096 + tid * 8]);        \
            gl_lds16(pa + 2048, &As[(buf) * 8192 + jj * 4096 + 2048 + tid * 8]); \
            gl_lds16(pb,        &Bs[(buf) * 4096 + jj * 2048 + tid * 8]);  } }

        f32x4 acc[2][4] = {};
        const int ga = (wave >> 1) * 256 + quad * 64 + (wave & 1) * 32; // A granule base
        const int gb = quad * 64;                                       // B granule base

        DMA_STAGE2(0, 0);
#pragma unroll 1
        for (int s = 0; s < 33; ++s) {
            const int cur = s & 1;
            __syncthreads();               // drains vmcnt(0): buf[cur] ready
            bf16x8 af[2][2], bfr[2][4];
#pragma unroll
            for (int jj = 0; jj < 2; ++jj) {
#pragma unroll
                for (int t = 0; t < 2; ++t)
                    af[jj][t]  = *(const bf16x8*)&As[cur * 8192 + jj * 4096 + (ga + t * 16 + l15) * 8];
#pragma unroll
                for (int t = 0; t < 4; ++t)
                    bfr[jj][t] = *(const bf16x8*)&Bs[cur * 4096 + jj * 2048 + (gb + t * 16 + l15) * 8];
            }
            if (s + 1 < 33) DMA_STAGE2(cur ^ 1, (s + 1) * 2);
#pragma unroll
            for (int jj = 0; jj < 2; ++jj)
#pragma unroll
                for (int rt = 0; rt < 2; ++rt)
#pragma unroll
                    for (int ct = 0; ct < 4; ++ct)
                        acc[rt][ct] = __builtin_amdgcn_mfma_f32_16x16x32_bf16(
                            af[jj][rt], bfr[jj][ct], acc[rt][ct], 0, 0, 0);
        }
#undef DMA_STAGE2

        // Epilogue. C/D layout: col = lane&15, row = quad*4 + reg
#pragma unroll
        for (int rt = 0; rt < 2; ++rt) {
            const int nbase = n0 + wave * 32 + rt * 16 + quad * 4;
#pragma unroll
            for (int ct = 0; ct < 4; ++ct) {
                const int c = ct * 16 + l15;
#pragma unroll
                for (int r = 0; r < 4; ++r) {
                    int n = nbase + r;
                    if (n < N_NODES)
                        Ybf[((size_t)b * N_NODES + n) * DIM + c] = (bf16)acc[rt][ct][r];
                }
                if (nbase + 4 <= N_NODES) {
                    const int kb2 = nbase >> 5;
                    const int kq  = (nbase & 31) >> 3;
                    const int j4  = nbase & 7;       // 0 or 4
                    bf16x4pk pk;
                    pk.v[0] = (bf16)acc[rt][ct][0];
                    pk.v[1] = (bf16)acc[rt][ct][1];
                    pk.v[2] = (bf16)acc[rt][ct][2];
                    pk.v[3] = (bf16)acc[rt][ct][3];
                    *(bf16x4pk*)&Ytp[((size_t)(b * KB3 + kb2) * 256 + kq * 64 + c) * 8 + j4] = pk;
                }
            }
        }
    } else {
        // ================= prep_W role (coarse, R4-proven body) ============
        // W[n][col] = sum_d embp[n][d] * wpT2[col][d]  (bf16 out)
        bf16 (*Cs)[264] = (bf16(*)[264])smem;    // 16 x 264 x 2B = 8.4 KB

        const int pid     = bid - 512;
        const int colbase = (pid % 48) * 256;
        const int ng0     = (pid / 48) * 5;

        bf16x8 bfr[4];
#pragma unroll
        for (int ct = 0; ct < 4; ++ct) {
            const int col = colbase + wave * 64 + ct * 16 + l15;
            bfr[ct] = *(const bf16x8*)&wpT2[(size_t)col * 32 + quad * 8];
        }
        bf16x8 afs[5];
#pragma unroll
        for (int g = 0; g < 5; ++g)
            afs[g] = *(const bf16x8*)&embp[(size_t)((ng0 + g) * 16 + l15) * 32 + quad * 8];
        const f32x4 zero = {};

#pragma unroll
        for (int g = 0; g < 5; ++g) {
            const int n0 = (ng0 + g) * 16;
#pragma unroll
            for (int ct = 0; ct < 4; ++ct) {
                f32x4 acc = __builtin_amdgcn_mfma_f32_16x16x32_bf16(afs[g], bfr[ct], zero, 0, 0, 0);
#pragma unroll
                for (int r = 0; r < 4; ++r)
                    Cs[quad * 4 + r][wave * 64 + ct * 16 + l15] = (bf16)acc[r];
            }
            __syncthreads();
            {
                const int row = tid >> 4;
                const int c16 = (tid & 15) * 16;
                bf16x8 v0 = *(const bf16x8*)&Cs[row][c16];
                bf16x8 v1 = *(const bf16x8*)&Cs[row][c16 + 8];
                bf16* dst = &W[(size_t)(n0 + row) * WCOLS + colbase + c16];
                *(bf16x8*)dst       = v0;
                *(bf16x8*)(dst + 8) = v1;
            }
            __syncthreads();   // Cs fully consumed before next group's MFMA
        }
    }
}

// ---------------------------------------------------------------------------
// Kernel 3b: spmm2 — R4-proven structure (dbuf 3-kb stages, 72 KB LDS).
// ---------------------------------------------------------------------------
__global__ __launch_bounds__(256, 2) void spmm_pack(
    const bf16* __restrict__ Ap, const bf16* __restrict__ Btp,
    bf16* __restrict__ Ybf)
{
    const int i = blockIdx.x;            // 0..511
    const int kx = i & 7, j = i >> 3;    // kx = XCD (dispatch round-robin)
    const int ntB = (j & 7) + 8 * (kx & 1);
    const int b   = ((j >> 3) << 2) + (kx >> 1);
    const int n0  = ntB * 128;
    const int tid = threadIdx.x;
    const int lane = tid & 63, wave = tid >> 6;
    const int l15 = lane & 15, quad = lane >> 4;

    __shared__ bf16 As[2][3 * 4096];   // 24 KB per buffer (128 rows x 3x32 k)
    __shared__ bf16 Bs[2][3 * 2048];   // 12 KB per buffer ( 64 cols x 3x32 k)

    const bf16* aslab = Ap  + (size_t)(ntB * 2) * 2048 + tid * 8;  // + kb*65536
    const bf16* bslab = Btp + (size_t)(b * KB3) * 2048 + tid * 8;  // + kb*2048

#define DMA_STAGE(buf, kb0_) {                                        \
        _Pragma("unroll")                                             \
        for (int jj = 0; jj < 3; ++jj) {                              \
            const bf16* pa = aslab + (size_t)(kb0_ + jj) * (32 * 2048);\
            const bf16* pb = bslab + (size_t)(kb0_ + jj) * 2048;      \
            gl_lds16(pa,        &As[buf][jj * 4096 + tid * 8]);       \
            gl_lds16(pa + 2048, &As[buf][jj * 4096 + 2048 + tid * 8]);\
            gl_lds16(pb,        &Bs[buf][jj * 2048 + tid * 8]);  } }

    f32x4 acc[2][4] = {};
    const int ga = (wave >> 1) * 256 + quad * 64 + (wave & 1) * 32; // A granule base
    const int gb = quad * 64;                                       // B granule base

    DMA_STAGE(0, 0);
#pragma unroll 1
    for (int s = 0; s < 22; ++s) {
        const int cur = s & 1;
        __syncthreads();               // drains vmcnt(0): buf[cur] ready
        bf16x8 af[3][2], bfr[3][4];
#pragma unroll
        for (int jj = 0; jj < 3; ++jj) {
#pragma unroll
            for (int t = 0; t < 2; ++t)
                af[jj][t]  = *(const bf16x8*)&As[cur][jj * 4096 + (ga + t * 16 + l15) * 8];
#pragma unroll
            for (int t = 0; t < 4; ++t)
                bfr[jj][t] = *(const bf16x8*)&Bs[cur][jj * 2048 + (gb + t * 16 + l15) * 8];
        }
        if (s + 1 < 22) DMA_STAGE(cur ^ 1, (s + 1) * 3);
#pragma unroll
        for (int jj = 0; jj < 3; ++jj)
#pragma unroll
            for (int rt = 0; rt < 2; ++rt)
#pragma unroll
                for (int ct = 0; ct < 4; ++ct)
                    acc[rt][ct] = __builtin_amdgcn_mfma_f32_16x16x32_bf16(
                        af[jj][rt], bfr[jj][ct], acc[rt][ct], 0, 0, 0);
    }
#undef DMA_STAGE

    // Epilogue. C/D layout: col = lane&15, row = quad*4 + reg
#pragma unroll
    for (int rt = 0; rt < 2; ++rt) {
        const int nbase = n0 + wave * 32 + rt * 16 + quad * 4;
#pragma unroll
        for (int ct = 0; ct < 4; ++ct) {
            const int c = ct * 16 + l15;
#pragma unroll
            for (int r = 0; r < 4; ++r) {
                int n = nbase + r;
                if (n < N_NODES)
                    Ybf[((size_t)b * N_NODES + n) * DIM + c] = (bf16)acc[rt][ct][r];
            }
        }
    }
}

// ---------------------------------------------------------------------------
// Kernel 5: per-node combine (bf16 inputs) — proven baseline form.
// ---------------------------------------------------------------------------
__global__ __launch_bounds__(256) void combine_node(
    const bf16* __restrict__ xbf, const bf16* __restrict__ y1bf,
    const bf16* __restrict__ y2bf, const float* __restrict__ emb,
    const float* __restrict__ bp, const bf16* __restrict__ W,
    float* __restrict__ out)
{
    const int n   = blockIdx.x;
    const int tid = threadIdx.x;
    const int lane = tid & 63, wave = tid >> 6;
    const int l15 = lane & 15, quad = lane >> 4;

    __shared__ bf16 As[BATCH][200];
    __shared__ bf16 Ws[DIM][200];
    __shared__ float bias_s[DIM];
    __shared__ float emb_s[EMB];

    if (tid < EMB) emb_s[tid] = emb[n * EMB + tid];

    {
        const int b  = tid >> 3;
        const int c8 = (tid & 7) * 8;
        const size_t base = ((size_t)b * N_NODES + n) * DIM + c8;
        bf16x8 vx = *(const bf16x8*)&xbf [base];
        bf16x8 v1 = *(const bf16x8*)&y1bf[base];
        bf16x8 v2 = *(const bf16x8*)&y2bf[base];
        bf16x8 p2;
#pragma unroll
        for (int e = 0; e < 8; ++e)
            p2[e] = (bf16)(2.0f * (float)v2[e] - (float)vx[e]);
        *(bf16x8*)&As[b][c8]       = vx;
        *(bf16x8*)&As[b][64 + c8]  = v1;
        *(bf16x8*)&As[b][128 + c8] = p2;
    }
    {
        const bf16* Wn = W + (size_t)n * WCOLS;
#pragma unroll
        for (int jj = 0; jj < 6; ++jj) {
            int chunk = jj * 256 + tid;
            int o  = chunk / 24;
            int kc = chunk - o * 24;
            bf16x8 v = *(const bf16x8*)&Wn[(size_t)chunk * 8];
            *(bf16x8*)&Ws[o][kc * 8] = v;
        }
    }
    __syncthreads();

    if (tid < DIM) {
        float s = 0.0f;
#pragma unroll
        for (int d = 0; d < EMB; ++d) s += emb_s[d] * bp[d * DIM + tid];
        bias_s[tid] = s;
    }

    bf16x8 af[2][6];
#pragma unroll
    for (int mt = 0; mt < 2; ++mt)
#pragma unroll
        for (int ks = 0; ks < 6; ++ks)
            af[mt][ks] = *(const bf16x8*)&As[mt * 16 + l15][ks * 32 + quad * 8];

    f32x4 acc[2] = {};
#pragma unroll
    for (int ks = 0; ks < 6; ++ks) {
        bf16x8 bfr = *(const bf16x8*)&Ws[wave * 16 + l15][ks * 32 + quad * 8];
        acc[0] = __builtin_amdgcn_mfma_f32_16x16x32_bf16(af[0][ks], bfr, acc[0], 0, 0, 0);
        acc[1] = __builtin_amdgcn_mfma_f32_16x16x32_bf16(af[1][ks], bfr, acc[1], 0, 0, 0);
    }
    __syncthreads();

    const int o = wave * 16 + l15;
    const float bv = bias_s[o];
#pragma unroll
    for (int mt = 0; mt < 2; ++mt)
#pragma unroll
        for (int r = 0; r < 4; ++r) {
            int b = mt * 16 + quad * 4 + r;
            out[((size_t)b * N_NODES + n) * DIM + o] = acc[mt][r] + bv;
        }
}

// ---------------------------------------------------------------------------
extern "C" void kernel_launch(void* const* d_in, const int* in_sizes, int n_in,
                              void* d_out, int out_size, void* d_ws, size_t ws_size,
                              hipStream_t stream) {
    const float* x   = (const float*)d_in[0];  // [32,2000,64]
    const float* emb = (const float*)d_in[1];  // [2000,16]
    const float* nv1 = (const float*)d_in[2];  // [2000,16]
    const float* nv2 = (const float*)d_in[3];  // [16,2000]
    const float* wp  = (const float*)d_in[4];  // [16,3,64,64]
    const float* bp  = (const float*)d_in[5];  // [16,64]
    float* out = (float*)d_out;                // [32,2000,64]

    char* w = (char*)d_ws;
    bf16* Sp   = (bf16*)w;  w += (size_t)KB3 * NP * 32 * 2;           //  8.65 MB
    bf16* xTp  = (bf16*)w;  w += (size_t)BATCH * KB3 * DIM * 32 * 2;  //  8.65 MB
    bf16* y1Tp = (bf16*)w;  w += (size_t)BATCH * KB3 * DIM * 32 * 2;  //  8.65 MB
    bf16* xbf  = (bf16*)w;  w += (size_t)BATCH * N_NODES * DIM * 2;   //  8.19 MB
    bf16* y1bf = (bf16*)w;  w += (size_t)BATCH * N_NODES * DIM * 2;   //  8.19 MB
    bf16* y2bf = (bf16*)w;  w += (size_t)BATCH * N_NODES * DIM * 2;   //  8.19 MB
    bf16* wpT2 = (bf16*)w;  w += (size_t)WCOLS * 32 * 2;              //  0.79 MB
    bf16* embp = (bf16*)w;  w += (size_t)N_NODES * 32 * 2;            //  0.13 MB
    bf16* W    = (bf16*)w;                                            // 49.15 MB

    prep_fused<<<PREP_BLOCKS, 256, 0, stream>>>(
        nv1, nv2, Sp, x, xTp, xbf, wp, emb, wpT2, embp,
        Sp + (size_t)63 * NP * 32);
    // spmm1 + prep_W colocated: 512 spmm blocks + 1200 coarse prep_W blocks
    spmm1_plus<<<512 + PW_BLOCKS, 256, 0, stream>>>(Sp, xTp, y1bf, y1Tp, embp, wpT2, W);
    spmm_pack<<<512, 256, 0, stream>>>(Sp, y1Tp, y2bf);
    combine_node<<<N_NODES, 256, 0, stream>>>(xbf, y1bf, y2bf, emb, bp, W, out);
}

// Round 10
// 158.449 us; speedup vs baseline: 1.1119x; 1.0958x over previous
//
#include <hip/hip_runtime.h>

#define N_NODES 2000
#define NP      2048    // Sp n-dim padding
#define KB      63      // real k-blocks (k = 2000 padded to 2016 in-block)
#define KB3     66      // padded k-blocks: slabs 63..65 of Sp zero-filled (A=0)
#define BATCH   32
#define DIM     64      // DIM_IN == DIM_OUT
#define EMB     16
#define KI      192     // CHEB_K * DIM_IN
#define WCOLS   12288   // DIM_OUT * KI

typedef __bf16 bf16;
typedef __attribute__((ext_vector_type(8))) __bf16 bf16x8;
typedef __attribute__((ext_vector_type(4))) float  f32x4;

struct alignas(8) bf16x4pk { bf16 v[4]; };

// Async global->LDS DMA, 16 B per lane (lane-contiguous within each wave).
__device__ __forceinline__ void gl_lds16(const bf16* g, bf16* l) {
    __builtin_amdgcn_global_load_lds(
        (__attribute__((address_space(1))) void*)(g),
        (__attribute__((address_space(3))) void*)(l), 16, 0, 0);
}

// Packed tile format (4 KB = 256 granules of 16 B) for a 64(row) x 32(k) tile:
//   granule(q, r) = q*64 + r holds elements [row=r][k = q*8 .. q*8+7]
// Fragment read hits 16 consecutive granules per quad-phase -> conflict-free
// ds_read_b128 (SQ_LDS_BANK_CONFLICT == 0 across all rounds).

#define Z0   (WCOLS * 32)
#define Z1   (Z0 + N_NODES * 32)
#define Z2   (Z1 + 3 * NP * 32)
// fused-prep grid: [0,2000) softmax rows | [2000,3024) transpose tiles |
// [3024, 3024+2554) prep_small chunks  (Z2/256 == 2554 exactly)
#define PREP_SM_BLK   2554
#define PREP_BLOCKS   (N_NODES + 1024 + PREP_SM_BLK)

// prep_W coarse blocks: 48 colbases x 25 strips (5 n-groups each) = 1200
#define PW_BLOCKS 1200

// ---------------------------------------------------------------------------
// Kernel A (fused): softmax -> Sp packed | x transpose-pack | wpT2/embp/zero
// R4-proven form (VGPR ~36, ~48% occupancy). R9's wave-per-row softmax
// rewrite hit VGPR 220 / 9% occupancy (full-unroll register explosion) and
// regressed prep to 44 us — reverted.
// ---------------------------------------------------------------------------
__global__ __launch_bounds__(256) void prep_fused(
    const float* __restrict__ nv1, const float* __restrict__ nv2,
    bf16* __restrict__ Sp,
    const float* __restrict__ X, bf16* __restrict__ Xtp, bf16* __restrict__ Xbf,
    const float* __restrict__ wp, const float* __restrict__ emb,
    bf16* __restrict__ wpT2, bf16* __restrict__ embp, bf16* __restrict__ Sp63)
{
    const int bid = blockIdx.x;
    const int tid = threadIdx.x;

    if (bid < N_NODES) {
        // ----- softmax(relu(nv1@nv2)) row -> packed Sp tiles -----
        const int row = bid;
        const int j0  = tid * 8;
        __shared__ float sa[EMB];
        __shared__ float wred[4];
        __shared__ float bcast;
        if (tid < EMB) sa[tid] = nv1[row * EMB + tid];
        __syncthreads();

        const bool active = (tid < 250);
        float v[8] = {0,0,0,0,0,0,0,0};
        if (active) {
#pragma unroll
            for (int d = 0; d < EMB; ++d) {
                const float sd = sa[d];
                const float4 q0 = *(const float4*)&nv2[d * N_NODES + j0];
                const float4 q1 = *(const float4*)&nv2[d * N_NODES + j0 + 4];
                v[0] += sd * q0.x; v[1] += sd * q0.y; v[2] += sd * q0.z; v[3] += sd * q0.w;
                v[4] += sd * q1.x; v[5] += sd * q1.y; v[6] += sd * q1.z; v[7] += sd * q1.w;
            }
        }
        float lmax = 0.0f;
#pragma unroll
        for (int jj = 0; jj < 8; ++jj) { v[jj] = fmaxf(v[jj], 0.0f); lmax = fmaxf(lmax, v[jj]); }
#pragma unroll
        for (int off = 32; off > 0; off >>= 1)
            lmax = fmaxf(lmax, __shfl_down(lmax, off, 64));
        if ((tid & 63) == 0) wred[tid >> 6] = lmax;
        __syncthreads();
        if (tid == 0) bcast = fmaxf(fmaxf(wred[0], wred[1]), fmaxf(wred[2], wred[3]));
        __syncthreads();
        const float rmax = bcast;

        float lsum = 0.0f;
        if (active) {
#pragma unroll
            for (int jj = 0; jj < 8; ++jj) { v[jj] = __expf(v[jj] - rmax); lsum += v[jj]; }
        }
#pragma unroll
        for (int off = 32; off > 0; off >>= 1)
            lsum += __shfl_down(lsum, off, 64);
        if ((tid & 63) == 0) wred[tid >> 6] = lsum;
        __syncthreads();
        if (tid == 0) bcast = wred[0] + wred[1] + wred[2] + wred[3];
        __syncthreads();
        const float inv = 1.0f / bcast;

        if (tid < 252) {   // threads 250,251 write the k 2000..2015 zero pad
            bf16x8 pk;
#pragma unroll
            for (int jj = 0; jj < 8; ++jj)
                pk[jj] = (bf16)(active ? v[jj] * inv : 0.0f);
            const int kb = j0 >> 5, q = (j0 >> 3) & 3;
            const int nt = row >> 6, r = row & 63;
            *(bf16x8*)&Sp[((size_t)(kb * 32 + nt) * 256 + q * 64 + r) * 8] = pk;
        }
    } else if (bid < N_NODES + 1024) {
        // ----- x [b][m][c] fp32 -> xTp packed + xbf row-major bf16 -----
        const int t  = bid - N_NODES;
        const int b  = t >> 5;
        const int m0 = (t & 31) * 64;
        __shared__ bf16 T[64][72];
#pragma unroll
        for (int i = 0; i < 4; ++i) {
            int idx = i * 256 + tid;
            int r  = idx >> 4;
            int c4 = (idx & 15) * 4;
            int m  = m0 + r;
            float4 v = make_float4(0.f, 0.f, 0.f, 0.f);
            if (m < N_NODES)
                v = *(const float4*)&X[((size_t)b * N_NODES + m) * DIM + c4];
            bf16x4pk pk;
            pk.v[0] = (bf16)v.x; pk.v[1] = (bf16)v.y;
            pk.v[2] = (bf16)v.z; pk.v[3] = (bf16)v.w;
            if (m < N_NODES)
                *(bf16x4pk*)&Xbf[((size_t)b * N_NODES + m) * DIM + c4] = pk;
            T[c4 + 0][r] = pk.v[0];
            T[c4 + 1][r] = pk.v[1];
            T[c4 + 2][r] = pk.v[2];
            T[c4 + 3][r] = pk.v[3];
        }
        __syncthreads();
#pragma unroll
        for (int i = 0; i < 2; ++i) {
            int idx = i * 256 + tid;
            int c   = idx >> 3;
            int mch = idx & 7;
            int kb  = (m0 >> 5) + (mch >> 2);
            if (kb < KB) {
                int q = mch & 3;
                bf16x8 vv = *(const bf16x8*)&T[c][mch * 8];
                *(bf16x8*)&Xtp[((size_t)(b * KB3 + kb) * 256 + q * 64 + c) * 8] = vv;
            }
        }
    } else {
        // ----- wpT2 / embp pack + zero-fill Sp slabs 63..65 -----
        int idx = (bid - N_NODES - 1024) * 256 + tid;
        if (idx < Z0) {
            int col = idx >> 5, d = idx & 31;
            int o  = col / KI;
            int kk = col - o * KI;
            int cheb = kk >> 6, i = kk & 63;
            float v = (d < EMB) ? wp[(((d * 3 + cheb) * 64 + i) * 64) + o] : 0.0f;
            wpT2[idx] = (bf16)v;
        } else if (idx < Z1) {
            int j = idx - Z0;
            int n = j >> 5, d = j & 31;
            float v = (d < EMB) ? emb[n * EMB + d] : 0.0f;
            embp[j] = (bf16)v;
        } else if (idx < Z2) {
            Sp63[idx - Z1] = (bf16)0.0f;
        }
    }
}

// ---------------------------------------------------------------------------
// Kernel 3a (MERGED): spmm1 (2-kb stages, 48 KB LDS, 3 blocks/CU) + prep_W.
// Proven R4 form (159.6 us total). The spmm role sits at the documented
// ~320-360 TF plateau for this size/structure class: R5-R8 showed counted
// vmcnt rings, reg-direct, and 2x occupancy all leave it at 43-49 us.
// ---------------------------------------------------------------------------
__global__ __launch_bounds__(256, 3) void spmm1_plus(
    const bf16* __restrict__ Ap, const bf16* __restrict__ Btp,
    bf16* __restrict__ Ybf, bf16* __restrict__ Ytp,
    const bf16* __restrict__ embp, const bf16* __restrict__ wpT2,
    bf16* __restrict__ W)
{
    __shared__ __align__(16) char smem[49152];   // 48 KB: union of both roles
    const int bid  = blockIdx.x;
    const int tid  = threadIdx.x;
    const int lane = tid & 63, wave = tid >> 6;
    const int l15  = lane & 15, quad = lane >> 4;

    if (bid < 512) {
        // ================= spmm role =================
        bf16* As = (bf16*)smem;             // [2][2*4096]  (2 x 16 KB)
        bf16* Bs = (bf16*)(smem + 32768);   // [2][2*2048]  (2 x  8 KB)

        const int kx = bid & 7, j = bid >> 3;   // kx = XCD (dispatch round-robin)
        const int ntB = (j & 7) + 8 * (kx & 1);
        const int b   = ((j >> 3) << 2) + (kx >> 1);
        const int n0  = ntB * 128;

        const bf16* aslab = Ap  + (size_t)(ntB * 2) * 2048 + tid * 8;  // + kb*65536
        const bf16* bslab = Btp + (size_t)(b * KB3) * 2048 + tid * 8;  // + kb*2048

#define DMA_STAGE2(buf, kb0_) {                                          \
        _Pragma("unroll")                                                \
        for (int jj = 0; jj < 2; ++jj) {                                 \
            const bf16* pa = aslab + (size_t)(kb0_ + jj) * (32 * 2048);  \
            const bf16* pb = bslab + (size_t)(kb0_ + jj) * 2048;         \
            gl_lds16(pa,        &As[(buf) * 8192 + jj * 4096 + tid * 8]);        \
            gl_lds16(pa + 2048, &As[(buf) * 8192 + jj * 4096 + 2048 + tid * 8]); \
            gl_lds16(pb,        &Bs[(buf) * 4096 + jj * 2048 + tid * 8]);  } }

        f32x4 acc[2][4] = {};
        const int ga = (wave >> 1) * 256 + quad * 64 + (wave & 1) * 32; // A granule base
        const int gb = quad * 64;                                       // B granule base

        DMA_STAGE2(0, 0);
#pragma unroll 1
        for (int s = 0; s < 33; ++s) {
            const int cur = s & 1;
            __syncthreads();               // drains vmcnt(0): buf[cur] ready
            bf16x8 af[2][2], bfr[2][4];
#pragma unroll
            for (int jj = 0; jj < 2; ++jj) {
#pragma unroll
                for (int t = 0; t < 2; ++t)
                    af[jj][t]  = *(const bf16x8*)&As[cur * 8192 + jj * 4096 + (ga + t * 16 + l15) * 8];
#pragma unroll
                for (int t = 0; t < 4; ++t)
                    bfr[jj][t] = *(const bf16x8*)&Bs[cur * 4096 + jj * 2048 + (gb + t * 16 + l15) * 8];
            }
            if (s + 1 < 33) DMA_STAGE2(cur ^ 1, (s + 1) * 2);
#pragma unroll
            for (int jj = 0; jj < 2; ++jj)
#pragma unroll
                for (int rt = 0; rt < 2; ++rt)
#pragma unroll
                    for (int ct = 0; ct < 4; ++ct)
                        acc[rt][ct] = __builtin_amdgcn_mfma_f32_16x16x32_bf16(
                            af[jj][rt], bfr[jj][ct], acc[rt][ct], 0, 0, 0);
        }
#undef DMA_STAGE2

        // Epilogue. C/D layout: col = lane&15, row = quad*4 + reg
#pragma unroll
        for (int rt = 0; rt < 2; ++rt) {
            const int nbase = n0 + wave * 32 + rt * 16 + quad * 4;
#pragma unroll
            for (int ct = 0; ct < 4; ++ct) {
                const int c = ct * 16 + l15;
#pragma unroll
                for (int r = 0; r < 4; ++r) {
                    int n = nbase + r;
                    if (n < N_NODES)
                        Ybf[((size_t)b * N_NODES + n) * DIM + c] = (bf16)acc[rt][ct][r];
                }
                if (nbase + 4 <= N_NODES) {
                    const int kb2 = nbase >> 5;
                    const int kq  = (nbase & 31) >> 3;
                    const int j4  = nbase & 7;       // 0 or 4
                    bf16x4pk pk;
                    pk.v[0] = (bf16)acc[rt][ct][0];
                    pk.v[1] = (bf16)acc[rt][ct][1];
                    pk.v[2] = (bf16)acc[rt][ct][2];
                    pk.v[3] = (bf16)acc[rt][ct][3];
                    *(bf16x4pk*)&Ytp[((size_t)(b * KB3 + kb2) * 256 + kq * 64 + c) * 8 + j4] = pk;
                }
            }
        }
    } else {
        // ================= prep_W role (coarse, R4-proven body) ============
        // W[n][col] = sum_d embp[n][d] * wpT2[col][d]  (bf16 out)
        bf16 (*Cs)[264] = (bf16(*)[264])smem;    // 16 x 264 x 2B = 8.4 KB

        const int pid     = bid - 512;
        const int colbase = (pid % 48) * 256;
        const int ng0     = (pid / 48) * 5;

        bf16x8 bfr[4];
#pragma unroll
        for (int ct = 0; ct < 4; ++ct) {
            const int col = colbase + wave * 64 + ct * 16 + l15;
            bfr[ct] = *(const bf16x8*)&wpT2[(size_t)col * 32 + quad * 8];
        }
        bf16x8 afs[5];
#pragma unroll
        for (int g = 0; g < 5; ++g)
            afs[g] = *(const bf16x8*)&embp[(size_t)((ng0 + g) * 16 + l15) * 32 + quad * 8];
        const f32x4 zero = {};

#pragma unroll
        for (int g = 0; g < 5; ++g) {
            const int n0 = (ng0 + g) * 16;
#pragma unroll
            for (int ct = 0; ct < 4; ++ct) {
                f32x4 acc = __builtin_amdgcn_mfma_f32_16x16x32_bf16(afs[g], bfr[ct], zero, 0, 0, 0);
#pragma unroll
                for (int r = 0; r < 4; ++r)
                    Cs[quad * 4 + r][wave * 64 + ct * 16 + l15] = (bf16)acc[r];
            }
            __syncthreads();
            {
                const int row = tid >> 4;
                const int c16 = (tid & 15) * 16;
                bf16x8 v0 = *(const bf16x8*)&Cs[row][c16];
                bf16x8 v1 = *(const bf16x8*)&Cs[row][c16 + 8];
                bf16* dst = &W[(size_t)(n0 + row) * WCOLS + colbase + c16];
                *(bf16x8*)dst       = v0;
                *(bf16x8*)(dst + 8) = v1;
            }
            __syncthreads();   // Cs fully consumed before next group's MFMA
        }
    }
}

// ---------------------------------------------------------------------------
// Kernel 3b: spmm2 — proven structure (dbuf 3-kb stages, 72 KB LDS,
// 128n x 64c block, XCD-aware swizzle). No Ytp write needed.
// ---------------------------------------------------------------------------
__global__ __launch_bounds__(256, 2) void spmm_pack(
    const bf16* __restrict__ Ap, const bf16* __restrict__ Btp,
    bf16* __restrict__ Ybf)
{
    const int i = blockIdx.x;            // 0..511
    const int kx = i & 7, j = i >> 3;    // kx = XCD (dispatch round-robin)
    const int ntB = (j & 7) + 8 * (kx & 1);
    const int b   = ((j >> 3) << 2) + (kx >> 1);
    const int n0  = ntB * 128;
    const int tid = threadIdx.x;
    const int lane = tid & 63, wave = tid >> 6;
    const int l15 = lane & 15, quad = lane >> 4;

    __shared__ bf16 As[2][3 * 4096];   // 24 KB per buffer (128 rows x 3x32 k)
    __shared__ bf16 Bs[2][3 * 2048];   // 12 KB per buffer ( 64 cols x 3x32 k)

    const bf16* aslab = Ap  + (size_t)(ntB * 2) * 2048 + tid * 8;  // + kb*65536
    const bf16* bslab = Btp + (size_t)(b * KB3) * 2048 + tid * 8;  // + kb*2048

#define DMA_STAGE(buf, kb0_) {                                        \
        _Pragma("unroll")                                             \
        for (int jj = 0; jj < 3; ++jj) {                              \
            const bf16* pa = aslab + (size_t)(kb0_ + jj) * (32 * 2048);\
            const bf16* pb = bslab + (size_t)(kb0_ + jj) * 2048;      \
            gl_lds16(pa,        &As[buf][jj * 4096 + tid * 8]);       \
            gl_lds16(pa + 2048, &As[buf][jj * 4096 + 2048 + tid * 8]);\
            gl_lds16(pb,        &Bs[buf][jj * 2048 + tid * 8]);  } }

    f32x4 acc[2][4] = {};
    const int ga = (wave >> 1) * 256 + quad * 64 + (wave & 1) * 32; // A granule base
    const int gb = quad * 64;                                       // B granule base

    DMA_STAGE(0, 0);
#pragma unroll 1
    for (int s = 0; s < 22; ++s) {
        const int cur = s & 1;
        __syncthreads();               // drains vmcnt(0): buf[cur] ready
        bf16x8 af[3][2], bfr[3][4];
#pragma unroll
        for (int jj = 0; jj < 3; ++jj) {
#pragma unroll
            for (int t = 0; t < 2; ++t)
                af[jj][t]  = *(const bf16x8*)&As[cur][jj * 4096 + (ga + t * 16 + l15) * 8];
#pragma unroll
            for (int t = 0; t < 4; ++t)
                bfr[jj][t] = *(const bf16x8*)&Bs[cur][jj * 2048 + (gb + t * 16 + l15) * 8];
        }
        if (s + 1 < 22) DMA_STAGE(cur ^ 1, (s + 1) * 3);
#pragma unroll
        for (int jj = 0; jj < 3; ++jj)
#pragma unroll
            for (int rt = 0; rt < 2; ++rt)
#pragma unroll
                for (int ct = 0; ct < 4; ++ct)
                    acc[rt][ct] = __builtin_amdgcn_mfma_f32_16x16x32_bf16(
                        af[jj][rt], bfr[jj][ct], acc[rt][ct], 0, 0, 0);
    }
#undef DMA_STAGE

    // Epilogue. C/D layout: col = lane&15, row = quad*4 + reg
#pragma unroll
    for (int rt = 0; rt < 2; ++rt) {
        const int nbase = n0 + wave * 32 + rt * 16 + quad * 4;
#pragma unroll
        for (int ct = 0; ct < 4; ++ct) {
            const int c = ct * 16 + l15;
#pragma unroll
            for (int r = 0; r < 4; ++r) {
                int n = nbase + r;
                if (n < N_NODES)
                    Ybf[((size_t)b * N_NODES + n) * DIM + c] = (bf16)acc[rt][ct][r];
            }
        }
    }
}

// ---------------------------------------------------------------------------
// Kernel 5: per-node combine (bf16 inputs) — proven baseline form.
// ---------------------------------------------------------------------------
__global__ __launch_bounds__(256) void combine_node(
    const bf16* __restrict__ xbf, const bf16* __restrict__ y1bf,
    const bf16* __restrict__ y2bf, const float* __restrict__ emb,
    const float* __restrict__ bp, const bf16* __restrict__ W,
    float* __restrict__ out)
{
    const int n   = blockIdx.x;
    const int tid = threadIdx.x;
    const int lane = tid & 63, wave = tid >> 6;
    const int l15 = lane & 15, quad = lane >> 4;

    __shared__ bf16 As[BATCH][200];
    __shared__ bf16 Ws[DIM][200];
    __shared__ float bias_s[DIM];
    __shared__ float emb_s[EMB];

    if (tid < EMB) emb_s[tid] = emb[n * EMB + tid];

    {
        const int b  = tid >> 3;
        const int c8 = (tid & 7) * 8;
        const size_t base = ((size_t)b * N_NODES + n) * DIM + c8;
        bf16x8 vx = *(const bf16x8*)&xbf [base];
        bf16x8 v1 = *(const bf16x8*)&y1bf[base];
        bf16x8 v2 = *(const bf16x8*)&y2bf[base];
        bf16x8 p2;
#pragma unroll
        for (int e = 0; e < 8; ++e)
            p2[e] = (bf16)(2.0f * (float)v2[e] - (float)vx[e]);
        *(bf16x8*)&As[b][c8]       = vx;
        *(bf16x8*)&As[b][64 + c8]  = v1;
        *(bf16x8*)&As[b][128 + c8] = p2;
    }
    {
        const bf16* Wn = W + (size_t)n * WCOLS;
#pragma unroll
        for (int jj = 0; jj < 6; ++jj) {
            int chunk = jj * 256 + tid;
            int o  = chunk / 24;
            int kc = chunk - o * 24;
            bf16x8 v = *(const bf16x8*)&Wn[(size_t)chunk * 8];
            *(bf16x8*)&Ws[o][kc * 8] = v;
        }
    }
    __syncthreads();

    if (tid < DIM) {
        float s = 0.0f;
#pragma unroll
        for (int d = 0; d < EMB; ++d) s += emb_s[d] * bp[d * DIM + tid];
        bias_s[tid] = s;
    }

    bf16x8 af[2][6];
#pragma unroll
    for (int mt = 0; mt < 2; ++mt)
#pragma unroll
        for (int ks = 0; ks < 6; ++ks)
            af[mt][ks] = *(const bf16x8*)&As[mt * 16 + l15][ks * 32 + quad * 8];

    f32x4 acc[2] = {};
#pragma unroll
    for (int ks = 0; ks < 6; ++ks) {
        bf16x8 bfr = *(const bf16x8*)&Ws[wave * 16 + l15][ks * 32 + quad * 8];
        acc[0] = __builtin_amdgcn_mfma_f32_16x16x32_bf16(af[0][ks], bfr, acc[0], 0, 0, 0);
        acc[1] = __builtin_amdgcn_mfma_f32_16x16x32_bf16(af[1][ks], bfr, acc[1], 0, 0, 0);
    }
    __syncthreads();

    const int o = wave * 16 + l15;
    const float bv = bias_s[o];
#pragma unroll
    for (int mt = 0; mt < 2; ++mt)
#pragma unroll
        for (int r = 0; r < 4; ++r) {
            int b = mt * 16 + quad * 4 + r;
            out[((size_t)b * N_NODES + n) * DIM + o] = acc[mt][r] + bv;
        }
}

// ---------------------------------------------------------------------------
extern "C" void kernel_launch(void* const* d_in, const int* in_sizes, int n_in,
                              void* d_out, int out_size, void* d_ws, size_t ws_size,
                              hipStream_t stream) {
    const float* x   = (const float*)d_in[0];  // [32,2000,64]
    const float* emb = (const float*)d_in[1];  // [2000,16]
    const float* nv1 = (const float*)d_in[2];  // [2000,16]
    const float* nv2 = (const float*)d_in[3];  // [16,2000]
    const float* wp  = (const float*)d_in[4];  // [16,3,64,64]
    const float* bp  = (const float*)d_in[5];  // [16,64]
    float* out = (float*)d_out;                // [32,2000,64]

    char* w = (char*)d_ws;
    bf16* Sp   = (bf16*)w;  w += (size_t)KB3 * NP * 32 * 2;           //  8.65 MB
    bf16* xTp  = (bf16*)w;  w += (size_t)BATCH * KB3 * DIM * 32 * 2;  //  8.65 MB
    bf16* y1Tp = (bf16*)w;  w += (size_t)BATCH * KB3 * DIM * 32 * 2;  //  8.65 MB
    bf16* xbf  = (bf16*)w;  w += (size_t)BATCH * N_NODES * DIM * 2;   //  8.19 MB
    bf16* y1bf = (bf16*)w;  w += (size_t)BATCH * N_NODES * DIM * 2;   //  8.19 MB
    bf16* y2bf = (bf16*)w;  w += (size_t)BATCH * N_NODES * DIM * 2;   //  8.19 MB
    bf16* wpT2 = (bf16*)w;  w += (size_t)WCOLS * 32 * 2;              //  0.79 MB
    bf16* embp = (bf16*)w;  w += (size_t)N_NODES * 32 * 2;            //  0.13 MB
    bf16* W    = (bf16*)w;                                            // 49.15 MB

    prep_fused<<<PREP_BLOCKS, 256, 0, stream>>>(
        nv1, nv2, Sp, x, xTp, xbf, wp, emb, wpT2, embp,
        Sp + (size_t)63 * NP * 32);
    // spmm1 + prep_W colocated: 512 spmm blocks + 1200 coarse prep_W blocks
    spmm1_plus<<<512 + PW_BLOCKS, 256, 0, stream>>>(Sp, xTp, y1bf, y1Tp, embp, wpT2, W);
    spmm_pack<<<512, 256, 0, stream>>>(Sp, y1Tp, y2bf);
    combine_node<<<N_NODES, 256, 0, stream>>>(xbf, y1bf, y2bf, emb, bp, W, out);
}